// Round 18
// baseline (133.501 us; speedup 1.0000x reference)
//
#include <hip/hip_runtime.h>
#include <hip/hip_bf16.h>

#define HW 16384
#define NB 8
#define CIN 64

// snake tile geometry
#define WIN_R 18
#define WIN_C 26
#define CELLS (WIN_R * WIN_C)     // 468
#define CHUNKS (CELLS * 4)        // 1872 x 16B per ci-half
#define BUFB (CELLS * 64)         // 29952 bytes (one ci-half window)
#define WSLAB 18432               // shorts per (br,half) weight slab

typedef short short8 __attribute__((ext_vector_type(8)));
typedef short short4v __attribute__((ext_vector_type(4)));
typedef float f32x4 __attribute__((ext_vector_type(4)));
typedef _Float16 half8 __attribute__((ext_vector_type(8)));

// ---------------- ws layout (BYTE offsets) ----------------
#define XT_OFF   0
#define WRH_OFF  16777216
#define WOH_OFF  16924672
#define RAW_OFF  17000448
#define BNS_OFF  26437632
#define GNP_OFF  26439168
#define GNS_OFF  27487744
#define CVOUT_OFF 27489792
#define WS_NEED_F16 (27489792ull + 33554432ull)   // cvout: 16.7M f16

__device__ inline unsigned short f2h(float v) {
    _Float16 h = (_Float16)v;
    unsigned short u; __builtin_memcpy(&u, &h, 2);
    return u;
}
__device__ inline float h2f(unsigned short u) {
    _Float16 h; __builtin_memcpy(&h, &u, 2);
    return (float)h;
}

// x [b][ci][px] f32  ->  xt2 [b][half][px][32ci] f16.  (74-pad: conflict-free)
__global__ __launch_bounds__(256) void cvt_x(const float* __restrict__ x,
                                             unsigned short* __restrict__ xt2) {
    int blk = blockIdx.x;              // 512 = 8b * 64 tiles(256px)
    int b = blk >> 6;
    int px0 = (blk & 63) * 256;
    int t = threadIdx.x;
    __shared__ unsigned short lds[256][74];
    const float* xb = x + (size_t)b * CIN * HW + px0;
    for (int ci = 0; ci < 64; ++ci)
        lds[t][ci] = f2h(xb[ci * HW + t]);
    __syncthreads();
    int wv = t >> 6, l = t & 63;
    int chunk = l & 7;                 // 8 chunks of 8 ci
    int half = chunk >> 2, ci8 = chunk & 3;
    for (int it = 0; it < 8; ++it) {
        int row = it * 32 + wv * 8 + (l >> 3);
        short8 v = *(const short8*)&lds[row][chunk * 8];
        unsigned short* dst = xt2 + ((size_t)(b * 2 + half) * HW + px0 + row) * 32 + ci8 * 8;
        *(short8*)dst = v;
    }
}

// merged weight repack (f16), both lane-linear
__global__ __launch_bounds__(256) void repack_all(const float* __restrict__ cw0,
                                                  const float* __restrict__ cw1,
                                                  const float* __restrict__ ow0,
                                                  const float* __restrict__ ow1,
                                                  unsigned short* __restrict__ wrh3,
                                                  unsigned short* __restrict__ woh2) {
    int i = blockIdx.x * 256 + threadIdx.x;
    if (i < 2 * 2 * WSLAB) {
        int slab = i / WSLAB;          // br*2 + half
        int br = slab >> 1, chalf = slab & 1;
        int rem = i - slab * WSLAB;
        int e = rem & 7;
        int lane = (rem >> 3) & 63;
        int nnk = rem >> 9;
        int nn = nnk & 3, k = nnk >> 2;
        int co = nn * 16 + (lane & 15);
        int ci = chalf * 32 + (lane >> 4) * 8 + e;
        const float* w = br ? cw1 : cw0;
        wrh3[i] = f2h(w[(co * 64 + ci) * 9 + k]);
    }
    int j = i - 2 * 2 * WSLAB;
    if (j >= 0 && j < 18 * 2 * 64 * 8) {
        int e = j & 7;
        int lane = (j >> 3) & 63;
        int nn = (j >> 9) & 1;
        int s = j >> 10;               // tap*2 + half
        int tap = s >> 1, chalf = s & 1;
        int co = nn * 16 + (lane & 15);
        int ci = chalf * 32 + (lane >> 4) * 8 + e;
        float v = 0.f;
        if (co < 9)       v = ow0[(co * 64 + ci) * 9 + tap];
        else if (co < 18) v = ow1[(co * 64 + ci) * 9 + tap];
        woh2[j] = f2h(v);
    }
}

// offset 3x3 conv MFMA (f16) + fused BN partials; weights staged to LDS.
__global__ __launch_bounds__(256, 4) void off_mfma(const unsigned short* __restrict__ xt2,
                                                   const unsigned short* __restrict__ woh2,
                                                   float* __restrict__ off_raw,
                                                   float* __restrict__ bnp) {
    __shared__ __align__(16) unsigned char wlds[36864];

    int b = blockIdx.x & 7;
    int tgrp = blockIdx.x >> 3;
    int t = threadIdx.x;
    int wid = t >> 6, l = t & 63;
    int tile = tgrp * 4 + wid;
    int l15 = l & 15, kg = l >> 4;
    int px0 = tile * 32;
    int h = px0 >> 7;
    int w0 = px0 & 127;

#pragma unroll
    for (int it = 0; it < 9; ++it) {
        int d = it * 256 + t;
        __builtin_amdgcn_global_load_lds(
            (const __attribute__((address_space(1))) unsigned int*)(woh2 + d * 8),
            (__attribute__((address_space(3))) unsigned int*)(&wlds[0] + (it * 256 + wid * 64) * 16),
            16, 0, 0);
    }
    __syncthreads();

    f32x4 acc[2][2];
#pragma unroll
    for (int m = 0; m < 2; ++m)
#pragma unroll
        for (int nn = 0; nn < 2; ++nn) acc[m][nn] = (f32x4)(0.f);

#pragma unroll
    for (int s = 0; s < 18; ++s) {
        const int tap = s >> 1, half = s & 1;
        const int dy = tap / 3 - 1, dx = tap % 3 - 1;
        const unsigned short* plane = xt2 + (size_t)(b * 2 + half) * HW * 32;
        int y = h + dy;
        bool yok = (unsigned)y < 128u;
        int yc = min(max(y, 0), 127);
        half8 af[2];
#pragma unroll
        for (int m = 0; m < 2; ++m) {
            int xx = w0 + m * 16 + l15 + dx;
            bool ok = yok && ((unsigned)xx < 128u);
            int xc = min(max(xx, 0), 127);
            int o = yc * 128 + xc;
            half8 a = *(const half8*)&plane[(size_t)o * 32 + kg * 8];
            if (!ok) a = (half8)((_Float16)0.f);
            af[m] = a;
        }
        half8 bf[2];
#pragma unroll
        for (int nn = 0; nn < 2; ++nn)
            bf[nn] = *(const half8*)(wlds + ((s * 2 + nn) * 64 + l) * 16);
#pragma unroll
        for (int m = 0; m < 2; ++m)
#pragma unroll
            for (int nn = 0; nn < 2; ++nn)
                acc[m][nn] = __builtin_amdgcn_mfma_f32_16x16x32_f16(af[m], bf[nn], acc[m][nn], 0, 0, 0);
    }

    float s1[2] = {0.f, 0.f}, s2[2] = {0.f, 0.f};
#pragma unroll
    for (int m = 0; m < 2; ++m)
#pragma unroll
        for (int nn = 0; nn < 2; ++nn) {
            int co = nn * 16 + l15;
            f32x4 v = acc[m][nn];
            s1[nn] += v.x + v.y + v.z + v.w;
            s2[nn] += v.x * v.x + v.y * v.y + v.z * v.z + v.w * v.w;
            if (co < 18) {
                int br = co < 9 ? 0 : 1;
                int k = co - br * 9;
                int plane = (br * 8 + b) * 9 + k;
                int px = px0 + m * 16 + kg * 4;
                *(f32x4*)&off_raw[(size_t)plane * HW + px] = v;
            }
        }
#pragma unroll
    for (int off = 16; off <= 32; off <<= 1)
#pragma unroll
        for (int nn = 0; nn < 2; ++nn) {
            s1[nn] += __shfl_xor(s1[nn], off);
            s2[nn] += __shfl_xor(s2[nn], off);
        }
    if (l < 16) {
        int idx = ((l15 * 8 + b) * 512 + tile) * 2;
        bnp[idx] = s1[0]; bnp[idx + 1] = s2[0];
        if (l15 < 2) {
            int idx2 = (((16 + l15) * 8 + b) * 512 + tile) * 2;
            bnp[idx2] = s1[1]; bnp[idx2 + 1] = s2[1];
        }
    }
}

__device__ inline void block_reduce2(float& s1, float& s2) {
    __shared__ float sh[4][2];
#pragma unroll
    for (int o = 32; o > 0; o >>= 1) {
        s1 += __shfl_down(s1, o);
        s2 += __shfl_down(s2, o);
    }
    int wid = threadIdx.x >> 6, lane = threadIdx.x & 63;
    if (lane == 0) { sh[wid][0] = s1; sh[wid][1] = s2; }
    __syncthreads();
    if (threadIdx.x == 0)
        for (int i = 1; i < 4; ++i) { s1 += sh[i][0]; s2 += sh[i][1]; }
}

__global__ __launch_bounds__(256) void bn_fin2(const float* __restrict__ bnp,
                                               float* __restrict__ bn_stat) {
    int c = blockIdx.x;
    float s1 = 0.f, s2 = 0.f;
    for (int i = threadIdx.x; i < 4096; i += 256) {
        s1 += bnp[(c * 4096 + i) * 2];
        s2 += bnp[(c * 4096 + i) * 2 + 1];
    }
    block_reduce2(s1, s2);
    if (threadIdx.x == 0) {
        const float N = 8.f * 16384.f;
        float m = s1 / N;
        float var = s2 / N - m * m;
        bn_stat[c * 2] = m;
        bn_stat[c * 2 + 1] = rsqrtf(var + 1e-5f);
    }
}

// ---------------- snake conv; R17: unroll-3 k-loop + (256,4) bounds ----------
template <bool F16OUT>
__global__ __launch_bounds__(256, 4) void snake9(const unsigned short* __restrict__ xt2,
                                              const unsigned short* __restrict__ wrh3,
                                              const float* __restrict__ cb0,
                                              const float* __restrict__ cb1,
                                              const float* __restrict__ off_raw,
                                              const float* __restrict__ bn_stat,
                                              const float* __restrict__ bng0,
                                              const float* __restrict__ bnb0,
                                              const float* __restrict__ bng1,
                                              const float* __restrict__ bnb1,
                                              float* __restrict__ out,
                                              unsigned short* __restrict__ cvout,
                                              float* __restrict__ gnp) {
    __shared__ __align__(16) unsigned char winbuf[BUFB];
    __shared__ __align__(16) _Float16 fw_tab[4][9][32];     // f16: 2304 B
    __shared__ int cell_tab[4][9][32];

    int n = blockIdx.x;
    int b = n & 7;
    int rest = n >> 3;
    int br = rest >> 7;
    int tile = rest & 127;
    int h0 = (tile >> 3) * 8;
    int w0 = (tile & 7) * 16;
    int t = threadIdx.x;
    int wv = t >> 6, l = t & 63;
    int l15 = l & 15, kg = l >> 4;
    int lp = l & 31;

    int hrow = h0 + 2 * wv + (lp >> 4);
    int wcol = w0 + (lp & 15);
    int pxo = hrow * 128 + wcol;
    const float* bng = br ? bng1 : bng0;
    const float* bnb = br ? bnb1 : bnb0;

    f32x4 acc00 = (f32x4)(0.f), acc01 = (f32x4)(0.f), acc02 = (f32x4)(0.f), acc03 = (f32x4)(0.f);
    f32x4 acc10 = (f32x4)(0.f), acc11 = (f32x4)(0.f), acc12 = (f32x4)(0.f), acc13 = (f32x4)(0.f);

    const unsigned short* wbase = wrh3 + (size_t)(br * 2) * WSLAB;
    half8 nb0 = *(const half8*)(wbase + 0 * 512 + l * 8);
    half8 nb1 = *(const half8*)(wbase + 1 * 512 + l * 8);
    half8 nb2 = *(const half8*)(wbase + 2 * 512 + l * 8);
    half8 nb3 = *(const half8*)(wbase + 3 * 512 + l * 8);

#pragma unroll 1
    for (int half = 0; half < 2; ++half) {
        if (half == 1) __syncthreads();

        {
            const unsigned short* plane = xt2 + (size_t)(b * 2 + half) * HW * 32;
#pragma unroll
            for (int it = 0; it < 8; ++it) {
                int d = it * 256 + wv * 64 + l;
                if (d < CHUNKS) {
                    int cell = d >> 2;
                    int ci8 = (d & 3) ^ ((cell >> 1) & 3);
                    int s = cell / WIN_C;
                    int c = cell - s * WIN_C;
                    int row = min(max(h0 - 5 + s, 0), 127);
                    int col = min(max(w0 - 5 + c, 0), 127);
                    const unsigned short* src = plane + ((size_t)(row * 128 + col)) * 32 + ci8 * 8;
                    __builtin_amdgcn_global_load_lds(
                        (const __attribute__((address_space(1))) unsigned int*)src,
                        (__attribute__((address_space(3))) unsigned int*)(&winbuf[0] + (it * 256 + wv * 64) * 16),
                        16, 0, 0);
                }
            }
        }

        if (half == 0) {
            float tt[9];
#pragma unroll
            for (int k = 0; k < 9; ++k) {
                float raw = off_raw[(size_t)((br * 8 + b) * 9 + k) * HW + pxo];
                float mn = bn_stat[(br * 9 + k) * 2];
                float rs = bn_stat[(br * 9 + k) * 2 + 1];
                int ch = br ? k + 9 : k;
                tt[k] = tanhf((raw - mn) * rs * bng[ch] + bnb[ch]);
            }
            float cum[9];
            cum[4] = 0.f;
            cum[3] = tt[3]; cum[2] = tt[2] + cum[3]; cum[1] = tt[1] + cum[2]; cum[0] = tt[0] + cum[1];
            cum[5] = tt[5]; cum[6] = cum[5] + tt[6]; cum[7] = cum[6] + tt[7]; cum[8] = cum[7] + tt[8];
#pragma unroll
            for (int k = 0; k < 9; ++k) {
                int cell0, cell1; float fw;
                if (br == 0) {
                    int col = min(max(wcol + k - 4, 0), 127);
                    float yc = fminf(fmaxf((float)hrow + cum[k], 0.f), 127.f);
                    int y0 = (int)floorf(yc);
                    int y1 = min(y0 + 1, 127);
                    fw = yc - (float)y0;
                    int cs = col - (w0 - 5);
                    cell0 = (y0 - (h0 - 5)) * WIN_C + cs;
                    cell1 = (y1 - (h0 - 5)) * WIN_C + cs;
                } else {
                    int row = min(max(hrow + k - 4, 0), 127);
                    float xcf = fminf(fmaxf((float)wcol + cum[k], 0.f), 127.f);
                    int x0 = (int)floorf(xcf);
                    int x1 = min(x0 + 1, 127);
                    fw = xcf - (float)x0;
                    int rs = (row - (h0 - 5)) * WIN_C;
                    cell0 = rs + (x0 - (w0 - 5));
                    cell1 = rs + (x1 - (w0 - 5));
                }
                if (l < 32) {
                    cell_tab[wv][k][lp] = cell0 | (cell1 << 16);
                    fw_tab[wv][k][lp] = (_Float16)fw;
                }
            }
        }

        __syncthreads();

#pragma unroll 3
        for (int k = 0; k < 9; ++k) {
            half8 cb0f = nb0, cb1f = nb1, cb2f = nb2, cb3f = nb3;

            int kn2 = (k < 8) ? k + 1 : ((half == 0) ? 0 : 8);
            int hn2 = (k < 8) ? half : 1;
            const unsigned short* wn = wrh3 + (size_t)(br * 2 + hn2) * WSLAB
                                     + (size_t)(kn2 * 4) * 512 + l * 8;
            nb0 = *(const half8*)(wn + 0 * 512);
            nb1 = *(const half8*)(wn + 1 * 512);
            nb2 = *(const half8*)(wn + 2 * 512);
            nb3 = *(const half8*)(wn + 3 * 512);

            int cmp = cell_tab[wv][k][l15];
            int cmq = cell_tab[wv][k][l15 + 16];
            _Float16 fw0h = fw_tab[wv][k][l15];
            _Float16 fw1h = fw_tab[wv][k][l15 + 16];
            half8 f0s = (half8)(fw0h);
            half8 f0c = (half8)((_Float16)1.f - fw0h);
            half8 f1s = (half8)(fw1h);
            half8 f1c = (half8)((_Float16)1.f - fw1h);

            int c00 = cmp & 0xffff, c01 = ((unsigned)cmp) >> 16;
            int c10 = cmq & 0xffff, c11 = ((unsigned)cmq) >> 16;
            int o00 = c00 * 64 + ((kg ^ ((c00 >> 1) & 3)) << 4);
            int o01 = c01 * 64 + ((kg ^ ((c01 >> 1) & 3)) << 4);
            int o10 = c10 * 64 + ((kg ^ ((c10 >> 1) & 3)) << 4);
            int o11 = c11 * 64 + ((kg ^ ((c11 >> 1) & 3)) << 4);

            half8 a00 = *(const half8*)(winbuf + o00);
            half8 a01 = *(const half8*)(winbuf + o01);
            half8 a10 = *(const half8*)(winbuf + o10);
            half8 a11 = *(const half8*)(winbuf + o11);
            half8 af0 = a00 * f0c + a01 * f0s;
            half8 af1 = a10 * f1c + a11 * f1s;

            acc00 = __builtin_amdgcn_mfma_f32_16x16x32_f16(af0, cb0f, acc00, 0, 0, 0);
            acc01 = __builtin_amdgcn_mfma_f32_16x16x32_f16(af0, cb1f, acc01, 0, 0, 0);
            acc02 = __builtin_amdgcn_mfma_f32_16x16x32_f16(af0, cb2f, acc02, 0, 0, 0);
            acc03 = __builtin_amdgcn_mfma_f32_16x16x32_f16(af0, cb3f, acc03, 0, 0, 0);
            acc10 = __builtin_amdgcn_mfma_f32_16x16x32_f16(af1, cb0f, acc10, 0, 0, 0);
            acc11 = __builtin_amdgcn_mfma_f32_16x16x32_f16(af1, cb1f, acc11, 0, 0, 0);
            acc12 = __builtin_amdgcn_mfma_f32_16x16x32_f16(af1, cb2f, acc12, 0, 0, 0);
            acc13 = __builtin_amdgcn_mfma_f32_16x16x32_f16(af1, cb3f, acc13, 0, 0, 0);
        }
    }

    // epilogue: bias, store (f32 or f16), GN partials (always from f32)
    f32x4 accA[2][4] = {{acc00, acc01, acc02, acc03}, {acc10, acc11, acc12, acc13}};
    const float* cb = br ? cb1 : cb0;
    float s1[4], s2[4];
#pragma unroll
    for (int nn = 0; nn < 4; ++nn) { s1[nn] = 0.f; s2[nn] = 0.f; }
#pragma unroll
    for (int m = 0; m < 2; ++m) {
        int hm = h0 + 2 * wv + m;
#pragma unroll
        for (int nn = 0; nn < 4; ++nn) {
            int co = nn * 16 + l15;
            float bias = cb[co];
            f32x4 v = accA[m][nn];
            f32x4 r;
            r.x = v.x + bias; r.y = v.y + bias; r.z = v.z + bias; r.w = v.w + bias;
            s1[nn] += r.x + r.y + r.z + r.w;
            s2[nn] += r.x * r.x + r.y * r.y + r.z * r.z + r.w * r.w;
            size_t base = ((size_t)(b * 128 + br * 64 + co) << 14) + hm * 128 + w0 + kg * 4;
            if (F16OUT) {
                short4v p;
                p[0] = (short)f2h(r.x); p[1] = (short)f2h(r.y);
                p[2] = (short)f2h(r.z); p[3] = (short)f2h(r.w);
                *(short4v*)&cvout[base] = p;
            } else {
                *(f32x4*)&out[base] = r;
            }
        }
    }
#pragma unroll
    for (int off = 16; off <= 32; off <<= 1)
#pragma unroll
        for (int nn = 0; nn < 4; ++nn) {
            s1[nn] += __shfl_xor(s1[nn], off);
            s2[nn] += __shfl_xor(s2[nn], off);
        }
#pragma unroll
    for (int off = 1; off <= 2; off <<= 1)
#pragma unroll
        for (int nn = 0; nn < 4; ++nn) {
            s1[nn] += __shfl_xor(s1[nn], off);
            s2[nn] += __shfl_xor(s2[nn], off);
        }
    if ((l & 0x33) == 0) {
#pragma unroll
        for (int nn = 0; nn < 4; ++nn) {
            int g = nn * 4 + (l >> 2);
            size_t gi = ((size_t)((br * 8 + b) * 512 + tile * 4 + wv)) * 32 + g * 2;
            gnp[gi] = s1[nn];
            gnp[gi + 1] = s2[nn];
        }
    }
}

__global__ __launch_bounds__(256) void gn_reduce(const float* __restrict__ gnp,
                                                 float* __restrict__ gn_stat) {
    int sid = blockIdx.x;
    int bb = sid >> 4;
    int g = sid & 15;
    float s1 = 0.f, s2 = 0.f;
    int t = threadIdx.x;
#pragma unroll
    for (int j = 0; j < 2; ++j) {
        size_t gi = ((size_t)(bb * 512 + t * 2 + j)) * 32 + g * 2;
        s1 += gnp[gi];
        s2 += gnp[gi + 1];
    }
    block_reduce2(s1, s2);
    if (t == 0) {
        const float N = 4.f * 16384.f;
        float m = s1 / N;
        float var = s2 / N - m * m;
        gn_stat[sid * 2] = m;
        gn_stat[sid * 2 + 1] = rsqrtf(var + 1e-5f);
    }
}

template <bool F16IN>
__global__ __launch_bounds__(256) void gn_apply(float* __restrict__ out,
                                                const unsigned short* __restrict__ cvout,
                                                const float* __restrict__ gn_stat,
                                                const float* __restrict__ g0,
                                                const float* __restrict__ b0,
                                                const float* __restrict__ g1,
                                                const float* __restrict__ b1) {
    int i = blockIdx.x * 256 + threadIdx.x;
    size_t base = (size_t)i * 4;
    int c = (int)((base >> 14) & 127);
    int b = (int)(base >> 21);
    int br = c >> 6;
    int co = c & 63;
    int sid = (br * 8 + b) * 16 + (co >> 2);
    float m = gn_stat[sid * 2];
    float rs = gn_stat[sid * 2 + 1];
    const float* gg = br ? g1 : g0;
    const float* bb = br ? b1 : b0;
    float ga = gg[co] * rs, be = bb[co] - m * gg[co] * rs;
    f32x4 v;
    if (F16IN) {
        short4v p = *(const short4v*)&cvout[base];
        v.x = h2f((unsigned short)p[0]); v.y = h2f((unsigned short)p[1]);
        v.z = h2f((unsigned short)p[2]); v.w = h2f((unsigned short)p[3]);
    } else {
        v = *(f32x4*)&out[base];
    }
    f32x4 r;
    r.x = fmaxf(fmaf(v.x, ga, be), 0.f);
    r.y = fmaxf(fmaf(v.y, ga, be), 0.f);
    r.z = fmaxf(fmaf(v.z, ga, be), 0.f);
    r.w = fmaxf(fmaf(v.w, ga, be), 0.f);
    *(f32x4*)&out[base] = r;
}

extern "C" void kernel_launch(void* const* d_in, const int* in_sizes, int n_in,
                              void* d_out, int out_size, void* d_ws, size_t ws_size,
                              hipStream_t stream) {
    const float* x       = (const float*)d_in[0];
    const float* off_w0  = (const float*)d_in[1];
    const float* bn_g0   = (const float*)d_in[3];
    const float* bn_b0   = (const float*)d_in[4];
    const float* conv_w0 = (const float*)d_in[5];
    const float* conv_b0 = (const float*)d_in[6];
    const float* gn_g0   = (const float*)d_in[7];
    const float* gn_b0   = (const float*)d_in[8];
    const float* off_w1  = (const float*)d_in[9];
    const float* bn_g1   = (const float*)d_in[11];
    const float* bn_b1   = (const float*)d_in[12];
    const float* conv_w1 = (const float*)d_in[13];
    const float* conv_b1 = (const float*)d_in[14];
    const float* gn_g1   = (const float*)d_in[15];
    const float* gn_b1   = (const float*)d_in[16];

    char* ws = (char*)d_ws;
    unsigned short* xt2   = (unsigned short*)(ws + XT_OFF);
    unsigned short* wrh3  = (unsigned short*)(ws + WRH_OFF);
    unsigned short* woh2  = (unsigned short*)(ws + WOH_OFF);
    float* off_raw = (float*)(ws + RAW_OFF);
    float* bn_stat = (float*)(ws + BNS_OFF);
    float* gnp     = (float*)(ws + GNP_OFF);
    float* gn_stat = (float*)(ws + GNS_OFF);
    unsigned short* cvout = (unsigned short*)(ws + CVOUT_OFF);
    float* out = (float*)d_out;

    bool f16path = (ws_size >= WS_NEED_F16);

    cvt_x<<<512, 256, 0, stream>>>(x, xt2);
    repack_all<<<360, 256, 0, stream>>>(conv_w0, conv_w1, off_w0, off_w1, wrh3, woh2);
    off_mfma<<<1024, 256, 0, stream>>>(xt2, woh2, off_raw, gnp);
    bn_fin2<<<18, 256, 0, stream>>>(gnp, bn_stat);
    if (f16path) {
        snake9<true><<<2048, 256, 0, stream>>>(xt2, wrh3, conv_b0, conv_b1, off_raw, bn_stat,
                                               bn_g0, bn_b0, bn_g1, bn_b1, out, cvout, gnp);
        gn_reduce<<<256, 256, 0, stream>>>(gnp, gn_stat);
        gn_apply<true><<<16384, 256, 0, stream>>>(out, cvout, gn_stat, gn_g0, gn_b0, gn_g1, gn_b1);
    } else {
        snake9<false><<<2048, 256, 0, stream>>>(xt2, wrh3, conv_b0, conv_b1, off_raw, bn_stat,
                                                bn_g0, bn_b0, bn_g1, bn_b1, out, cvout, gnp);
        gn_reduce<<<256, 256, 0, stream>>>(gnp, gn_stat);
        gn_apply<false><<<16384, 256, 0, stream>>>(out, cvout, gn_stat, gn_g0, gn_b0, gn_g1, gn_b1);
    }
}

// Round 19
// 107.017 us; speedup vs baseline: 1.2475x; 1.2475x over previous
//
#include <hip/hip_runtime.h>
#include <hip/hip_bf16.h>

#define HW 16384
#define NB 8
#define CIN 64

// snake tile geometry
#define WIN_R 18
#define WIN_C 26
#define CELLS (WIN_R * WIN_C)     // 468
#define CHUNKS (CELLS * 4)        // 1872 x 16B per ci-half
#define BUFB (CELLS * 64)         // 29952 bytes (one ci-half window)
#define WSLAB 18432               // shorts per (br,half) weight slab

typedef short short8 __attribute__((ext_vector_type(8)));
typedef short short4v __attribute__((ext_vector_type(4)));
typedef float f32x4 __attribute__((ext_vector_type(4)));
typedef _Float16 half8 __attribute__((ext_vector_type(8)));

// ---------------- ws layout (BYTE offsets) ----------------
#define XT_OFF   0
#define WRH_OFF  16777216
#define WOH_OFF  16924672
#define RAW_OFF  17000448
#define BNS_OFF  26437632
#define GNP_OFF  26439168
#define GNS_OFF  27487744
#define CVOUT_OFF 27489792
#define WS_NEED_F16 (27489792ull + 33554432ull)   // cvout: 16.7M f16

__device__ inline unsigned short f2h(float v) {
    _Float16 h = (_Float16)v;
    unsigned short u; __builtin_memcpy(&u, &h, 2);
    return u;
}
__device__ inline float h2f(unsigned short u) {
    _Float16 h; __builtin_memcpy(&h, &u, 2);
    return (float)h;
}

// x [b][ci][px] f32  ->  xt2 [b][half][px][32ci] f16.  (74-pad: conflict-free)
__global__ __launch_bounds__(256) void cvt_x(const float* __restrict__ x,
                                             unsigned short* __restrict__ xt2) {
    int blk = blockIdx.x;              // 512 = 8b * 64 tiles(256px)
    int b = blk >> 6;
    int px0 = (blk & 63) * 256;
    int t = threadIdx.x;
    __shared__ unsigned short lds[256][74];
    const float* xb = x + (size_t)b * CIN * HW + px0;
    for (int ci = 0; ci < 64; ++ci)
        lds[t][ci] = f2h(xb[ci * HW + t]);
    __syncthreads();
    int wv = t >> 6, l = t & 63;
    int chunk = l & 7;                 // 8 chunks of 8 ci
    int half = chunk >> 2, ci8 = chunk & 3;
    for (int it = 0; it < 8; ++it) {
        int row = it * 32 + wv * 8 + (l >> 3);
        short8 v = *(const short8*)&lds[row][chunk * 8];
        unsigned short* dst = xt2 + ((size_t)(b * 2 + half) * HW + px0 + row) * 32 + ci8 * 8;
        *(short8*)dst = v;
    }
}

// merged weight repack (f16), both lane-linear
__global__ __launch_bounds__(256) void repack_all(const float* __restrict__ cw0,
                                                  const float* __restrict__ cw1,
                                                  const float* __restrict__ ow0,
                                                  const float* __restrict__ ow1,
                                                  unsigned short* __restrict__ wrh3,
                                                  unsigned short* __restrict__ woh2) {
    int i = blockIdx.x * 256 + threadIdx.x;
    if (i < 2 * 2 * WSLAB) {
        int slab = i / WSLAB;          // br*2 + half
        int br = slab >> 1, chalf = slab & 1;
        int rem = i - slab * WSLAB;
        int e = rem & 7;
        int lane = (rem >> 3) & 63;
        int nnk = rem >> 9;
        int nn = nnk & 3, k = nnk >> 2;
        int co = nn * 16 + (lane & 15);
        int ci = chalf * 32 + (lane >> 4) * 8 + e;
        const float* w = br ? cw1 : cw0;
        wrh3[i] = f2h(w[(co * 64 + ci) * 9 + k]);
    }
    int j = i - 2 * 2 * WSLAB;
    if (j >= 0 && j < 18 * 2 * 64 * 8) {
        int e = j & 7;
        int lane = (j >> 3) & 63;
        int nn = (j >> 9) & 1;
        int s = j >> 10;               // tap*2 + half
        int tap = s >> 1, chalf = s & 1;
        int co = nn * 16 + (lane & 15);
        int ci = chalf * 32 + (lane >> 4) * 8 + e;
        float v = 0.f;
        if (co < 9)       v = ow0[(co * 64 + ci) * 9 + tap];
        else if (co < 18) v = ow1[(co * 64 + ci) * 9 + tap];
        woh2[j] = f2h(v);
    }
}

// offset 3x3 conv MFMA (f16) + fused BN partials; weights staged to LDS.
__global__ __launch_bounds__(256, 4) void off_mfma(const unsigned short* __restrict__ xt2,
                                                   const unsigned short* __restrict__ woh2,
                                                   float* __restrict__ off_raw,
                                                   float* __restrict__ bnp) {
    __shared__ __align__(16) unsigned char wlds[36864];

    int b = blockIdx.x & 7;
    int tgrp = blockIdx.x >> 3;
    int t = threadIdx.x;
    int wid = t >> 6, l = t & 63;
    int tile = tgrp * 4 + wid;
    int l15 = l & 15, kg = l >> 4;
    int px0 = tile * 32;
    int h = px0 >> 7;
    int w0 = px0 & 127;

#pragma unroll
    for (int it = 0; it < 9; ++it) {
        int d = it * 256 + t;
        __builtin_amdgcn_global_load_lds(
            (const __attribute__((address_space(1))) unsigned int*)(woh2 + d * 8),
            (__attribute__((address_space(3))) unsigned int*)(&wlds[0] + (it * 256 + wid * 64) * 16),
            16, 0, 0);
    }
    __syncthreads();

    f32x4 acc[2][2];
#pragma unroll
    for (int m = 0; m < 2; ++m)
#pragma unroll
        for (int nn = 0; nn < 2; ++nn) acc[m][nn] = (f32x4)(0.f);

#pragma unroll
    for (int s = 0; s < 18; ++s) {
        const int tap = s >> 1, half = s & 1;
        const int dy = tap / 3 - 1, dx = tap % 3 - 1;
        const unsigned short* plane = xt2 + (size_t)(b * 2 + half) * HW * 32;
        int y = h + dy;
        bool yok = (unsigned)y < 128u;
        int yc = min(max(y, 0), 127);
        half8 af[2];
#pragma unroll
        for (int m = 0; m < 2; ++m) {
            int xx = w0 + m * 16 + l15 + dx;
            bool ok = yok && ((unsigned)xx < 128u);
            int xc = min(max(xx, 0), 127);
            int o = yc * 128 + xc;
            half8 a = *(const half8*)&plane[(size_t)o * 32 + kg * 8];
            if (!ok) a = (half8)((_Float16)0.f);
            af[m] = a;
        }
        half8 bf[2];
#pragma unroll
        for (int nn = 0; nn < 2; ++nn)
            bf[nn] = *(const half8*)(wlds + ((s * 2 + nn) * 64 + l) * 16);
#pragma unroll
        for (int m = 0; m < 2; ++m)
#pragma unroll
            for (int nn = 0; nn < 2; ++nn)
                acc[m][nn] = __builtin_amdgcn_mfma_f32_16x16x32_f16(af[m], bf[nn], acc[m][nn], 0, 0, 0);
    }

    float s1[2] = {0.f, 0.f}, s2[2] = {0.f, 0.f};
#pragma unroll
    for (int m = 0; m < 2; ++m)
#pragma unroll
        for (int nn = 0; nn < 2; ++nn) {
            int co = nn * 16 + l15;
            f32x4 v = acc[m][nn];
            s1[nn] += v.x + v.y + v.z + v.w;
            s2[nn] += v.x * v.x + v.y * v.y + v.z * v.z + v.w * v.w;
            if (co < 18) {
                int br = co < 9 ? 0 : 1;
                int k = co - br * 9;
                int plane = (br * 8 + b) * 9 + k;
                int px = px0 + m * 16 + kg * 4;
                *(f32x4*)&off_raw[(size_t)plane * HW + px] = v;
            }
        }
#pragma unroll
    for (int off = 16; off <= 32; off <<= 1)
#pragma unroll
        for (int nn = 0; nn < 2; ++nn) {
            s1[nn] += __shfl_xor(s1[nn], off);
            s2[nn] += __shfl_xor(s2[nn], off);
        }
    if (l < 16) {
        int idx = ((l15 * 8 + b) * 512 + tile) * 2;
        bnp[idx] = s1[0]; bnp[idx + 1] = s2[0];
        if (l15 < 2) {
            int idx2 = (((16 + l15) * 8 + b) * 512 + tile) * 2;
            bnp[idx2] = s1[1]; bnp[idx2 + 1] = s2[1];
        }
    }
}

__device__ inline void block_reduce2(float& s1, float& s2) {
    __shared__ float sh[4][2];
#pragma unroll
    for (int o = 32; o > 0; o >>= 1) {
        s1 += __shfl_down(s1, o);
        s2 += __shfl_down(s2, o);
    }
    int wid = threadIdx.x >> 6, lane = threadIdx.x & 63;
    if (lane == 0) { sh[wid][0] = s1; sh[wid][1] = s2; }
    __syncthreads();
    if (threadIdx.x == 0)
        for (int i = 1; i < 4; ++i) { s1 += sh[i][0]; s2 += sh[i][1]; }
}

__global__ __launch_bounds__(256) void bn_fin2(const float* __restrict__ bnp,
                                               float* __restrict__ bn_stat) {
    int c = blockIdx.x;
    float s1 = 0.f, s2 = 0.f;
    for (int i = threadIdx.x; i < 4096; i += 256) {
        s1 += bnp[(c * 4096 + i) * 2];
        s2 += bnp[(c * 4096 + i) * 2 + 1];
    }
    block_reduce2(s1, s2);
    if (threadIdx.x == 0) {
        const float N = 8.f * 16384.f;
        float m = s1 / N;
        float var = s2 / N - m * m;
        bn_stat[c * 2] = m;
        bn_stat[c * 2 + 1] = rsqrtf(var + 1e-5f);
    }
}

// ---------------- snake conv (R16 exact: rolled loop, no bounds cap) ----------
template <bool F16OUT>
__global__ __launch_bounds__(256) void snake9(const unsigned short* __restrict__ xt2,
                                              const unsigned short* __restrict__ wrh3,
                                              const float* __restrict__ cb0,
                                              const float* __restrict__ cb1,
                                              const float* __restrict__ off_raw,
                                              const float* __restrict__ bn_stat,
                                              const float* __restrict__ bng0,
                                              const float* __restrict__ bnb0,
                                              const float* __restrict__ bng1,
                                              const float* __restrict__ bnb1,
                                              float* __restrict__ out,
                                              unsigned short* __restrict__ cvout,
                                              float* __restrict__ gnp) {
    __shared__ __align__(16) unsigned char winbuf[BUFB];
    __shared__ __align__(16) float fw_tab[4][9][32];
    __shared__ int cell_tab[4][9][32];

    int n = blockIdx.x;
    int b = n & 7;
    int rest = n >> 3;
    int br = rest >> 7;
    int tile = rest & 127;
    int h0 = (tile >> 3) * 8;
    int w0 = (tile & 7) * 16;
    int t = threadIdx.x;
    int wv = t >> 6, l = t & 63;
    int l15 = l & 15, kg = l >> 4;
    int lp = l & 31;

    int hrow = h0 + 2 * wv + (lp >> 4);
    int wcol = w0 + (lp & 15);
    int pxo = hrow * 128 + wcol;
    const float* bng = br ? bng1 : bng0;
    const float* bnb = br ? bnb1 : bnb0;

    f32x4 acc00 = (f32x4)(0.f), acc01 = (f32x4)(0.f), acc02 = (f32x4)(0.f), acc03 = (f32x4)(0.f);
    f32x4 acc10 = (f32x4)(0.f), acc11 = (f32x4)(0.f), acc12 = (f32x4)(0.f), acc13 = (f32x4)(0.f);

    const unsigned short* wbase = wrh3 + (size_t)(br * 2) * WSLAB;
    half8 nb0 = *(const half8*)(wbase + 0 * 512 + l * 8);
    half8 nb1 = *(const half8*)(wbase + 1 * 512 + l * 8);
    half8 nb2 = *(const half8*)(wbase + 2 * 512 + l * 8);
    half8 nb3 = *(const half8*)(wbase + 3 * 512 + l * 8);

#pragma unroll 1
    for (int half = 0; half < 2; ++half) {
        if (half == 1) __syncthreads();

        {
            const unsigned short* plane = xt2 + (size_t)(b * 2 + half) * HW * 32;
#pragma unroll
            for (int it = 0; it < 8; ++it) {
                int d = it * 256 + wv * 64 + l;
                if (d < CHUNKS) {
                    int cell = d >> 2;
                    int ci8 = (d & 3) ^ ((cell >> 1) & 3);
                    int s = cell / WIN_C;
                    int c = cell - s * WIN_C;
                    int row = min(max(h0 - 5 + s, 0), 127);
                    int col = min(max(w0 - 5 + c, 0), 127);
                    const unsigned short* src = plane + ((size_t)(row * 128 + col)) * 32 + ci8 * 8;
                    __builtin_amdgcn_global_load_lds(
                        (const __attribute__((address_space(1))) unsigned int*)src,
                        (__attribute__((address_space(3))) unsigned int*)(&winbuf[0] + (it * 256 + wv * 64) * 16),
                        16, 0, 0);
                }
            }
        }

        if (half == 0) {
            float tt[9];
#pragma unroll
            for (int k = 0; k < 9; ++k) {
                float raw = off_raw[(size_t)((br * 8 + b) * 9 + k) * HW + pxo];
                float mn = bn_stat[(br * 9 + k) * 2];
                float rs = bn_stat[(br * 9 + k) * 2 + 1];
                int ch = br ? k + 9 : k;
                tt[k] = tanhf((raw - mn) * rs * bng[ch] + bnb[ch]);
            }
            float cum[9];
            cum[4] = 0.f;
            cum[3] = tt[3]; cum[2] = tt[2] + cum[3]; cum[1] = tt[1] + cum[2]; cum[0] = tt[0] + cum[1];
            cum[5] = tt[5]; cum[6] = cum[5] + tt[6]; cum[7] = cum[6] + tt[7]; cum[8] = cum[7] + tt[8];
#pragma unroll
            for (int k = 0; k < 9; ++k) {
                int cell0, cell1; float fw;
                if (br == 0) {
                    int col = min(max(wcol + k - 4, 0), 127);
                    float yc = fminf(fmaxf((float)hrow + cum[k], 0.f), 127.f);
                    int y0 = (int)floorf(yc);
                    int y1 = min(y0 + 1, 127);
                    fw = yc - (float)y0;
                    int cs = col - (w0 - 5);
                    cell0 = (y0 - (h0 - 5)) * WIN_C + cs;
                    cell1 = (y1 - (h0 - 5)) * WIN_C + cs;
                } else {
                    int row = min(max(hrow + k - 4, 0), 127);
                    float xcf = fminf(fmaxf((float)wcol + cum[k], 0.f), 127.f);
                    int x0 = (int)floorf(xcf);
                    int x1 = min(x0 + 1, 127);
                    fw = xcf - (float)x0;
                    int rs = (row - (h0 - 5)) * WIN_C;
                    cell0 = rs + (x0 - (w0 - 5));
                    cell1 = rs + (x1 - (w0 - 5));
                }
                if (l < 32) {
                    cell_tab[wv][k][lp] = cell0 | (cell1 << 16);
                    fw_tab[wv][k][lp] = fw;
                }
            }
        }

        __syncthreads();

        int cm0 = cell_tab[wv][0][l15];
        int cm1 = cell_tab[wv][0][l15 + 16];

#pragma unroll 1
        for (int k = 0; k < 9; ++k) {
            half8 cb0f = nb0, cb1f = nb1, cb2f = nb2, cb3f = nb3;

            int kn2 = (k < 8) ? k + 1 : ((half == 0) ? 0 : 8);
            int hn2 = (k < 8) ? half : 1;
            const unsigned short* wn = wrh3 + (size_t)(br * 2 + hn2) * WSLAB
                                     + (size_t)(kn2 * 4) * 512 + l * 8;
            nb0 = *(const half8*)(wn + 0 * 512);
            nb1 = *(const half8*)(wn + 1 * 512);
            nb2 = *(const half8*)(wn + 2 * 512);
            nb3 = *(const half8*)(wn + 3 * 512);

            int knc = (k < 8) ? k + 1 : 8;
            int nc0 = cell_tab[wv][knc][l15];
            int nc1 = cell_tab[wv][knc][l15 + 16];

            float fw0 = fw_tab[wv][k][l15];
            float fw1 = fw_tab[wv][k][l15 + 16];
            half8 f0s = (half8)((_Float16)fw0);
            half8 f0c = (half8)((_Float16)(1.f - fw0));
            half8 f1s = (half8)((_Float16)fw1);
            half8 f1c = (half8)((_Float16)(1.f - fw1));

            int c00 = cm0 & 0xffff, c01 = ((unsigned)cm0) >> 16;
            int c10 = cm1 & 0xffff, c11 = ((unsigned)cm1) >> 16;
            int o00 = c00 * 64 + ((kg ^ ((c00 >> 1) & 3)) << 4);
            int o01 = c01 * 64 + ((kg ^ ((c01 >> 1) & 3)) << 4);
            int o10 = c10 * 64 + ((kg ^ ((c10 >> 1) & 3)) << 4);
            int o11 = c11 * 64 + ((kg ^ ((c11 >> 1) & 3)) << 4);

            half8 a00 = *(const half8*)(winbuf + o00);
            half8 a01 = *(const half8*)(winbuf + o01);
            half8 a10 = *(const half8*)(winbuf + o10);
            half8 a11 = *(const half8*)(winbuf + o11);
            half8 af0 = a00 * f0c + a01 * f0s;
            half8 af1 = a10 * f1c + a11 * f1s;

            acc00 = __builtin_amdgcn_mfma_f32_16x16x32_f16(af0, cb0f, acc00, 0, 0, 0);
            acc01 = __builtin_amdgcn_mfma_f32_16x16x32_f16(af0, cb1f, acc01, 0, 0, 0);
            acc02 = __builtin_amdgcn_mfma_f32_16x16x32_f16(af0, cb2f, acc02, 0, 0, 0);
            acc03 = __builtin_amdgcn_mfma_f32_16x16x32_f16(af0, cb3f, acc03, 0, 0, 0);
            acc10 = __builtin_amdgcn_mfma_f32_16x16x32_f16(af1, cb0f, acc10, 0, 0, 0);
            acc11 = __builtin_amdgcn_mfma_f32_16x16x32_f16(af1, cb1f, acc11, 0, 0, 0);
            acc12 = __builtin_amdgcn_mfma_f32_16x16x32_f16(af1, cb2f, acc12, 0, 0, 0);
            acc13 = __builtin_amdgcn_mfma_f32_16x16x32_f16(af1, cb3f, acc13, 0, 0, 0);

            cm0 = nc0;
            cm1 = nc1;
        }
    }

    // epilogue: bias, store (f32 or f16), GN partials (always from f32)
    f32x4 accA[2][4] = {{acc00, acc01, acc02, acc03}, {acc10, acc11, acc12, acc13}};
    const float* cb = br ? cb1 : cb0;
    float s1[4], s2[4];
#pragma unroll
    for (int nn = 0; nn < 4; ++nn) { s1[nn] = 0.f; s2[nn] = 0.f; }
#pragma unroll
    for (int m = 0; m < 2; ++m) {
        int hm = h0 + 2 * wv + m;
#pragma unroll
        for (int nn = 0; nn < 4; ++nn) {
            int co = nn * 16 + l15;
            float bias = cb[co];
            f32x4 v = accA[m][nn];
            f32x4 r;
            r.x = v.x + bias; r.y = v.y + bias; r.z = v.z + bias; r.w = v.w + bias;
            s1[nn] += r.x + r.y + r.z + r.w;
            s2[nn] += r.x * r.x + r.y * r.y + r.z * r.z + r.w * r.w;
            size_t base = ((size_t)(b * 128 + br * 64 + co) << 14) + hm * 128 + w0 + kg * 4;
            if (F16OUT) {
                short4v p;
                p[0] = (short)f2h(r.x); p[1] = (short)f2h(r.y);
                p[2] = (short)f2h(r.z); p[3] = (short)f2h(r.w);
                *(short4v*)&cvout[base] = p;
            } else {
                *(f32x4*)&out[base] = r;
            }
        }
    }
#pragma unroll
    for (int off = 16; off <= 32; off <<= 1)
#pragma unroll
        for (int nn = 0; nn < 4; ++nn) {
            s1[nn] += __shfl_xor(s1[nn], off);
            s2[nn] += __shfl_xor(s2[nn], off);
        }
#pragma unroll
    for (int off = 1; off <= 2; off <<= 1)
#pragma unroll
        for (int nn = 0; nn < 4; ++nn) {
            s1[nn] += __shfl_xor(s1[nn], off);
            s2[nn] += __shfl_xor(s2[nn], off);
        }
    if ((l & 0x33) == 0) {
#pragma unroll
        for (int nn = 0; nn < 4; ++nn) {
            int g = nn * 4 + (l >> 2);
            size_t gi = ((size_t)((br * 8 + b) * 512 + tile * 4 + wv)) * 32 + g * 2;
            gnp[gi] = s1[nn];
            gnp[gi + 1] = s2[nn];
        }
    }
}

__global__ __launch_bounds__(256) void gn_reduce(const float* __restrict__ gnp,
                                                 float* __restrict__ gn_stat) {
    int sid = blockIdx.x;
    int bb = sid >> 4;
    int g = sid & 15;
    float s1 = 0.f, s2 = 0.f;
    int t = threadIdx.x;
#pragma unroll
    for (int j = 0; j < 2; ++j) {
        size_t gi = ((size_t)(bb * 512 + t * 2 + j)) * 32 + g * 2;
        s1 += gnp[gi];
        s2 += gnp[gi + 1];
    }
    block_reduce2(s1, s2);
    if (t == 0) {
        const float N = 4.f * 16384.f;
        float m = s1 / N;
        float var = s2 / N - m * m;
        gn_stat[sid * 2] = m;
        gn_stat[sid * 2 + 1] = rsqrtf(var + 1e-5f);
    }
}

template <bool F16IN>
__global__ __launch_bounds__(256) void gn_apply(float* __restrict__ out,
                                                const unsigned short* __restrict__ cvout,
                                                const float* __restrict__ gn_stat,
                                                const float* __restrict__ g0,
                                                const float* __restrict__ b0,
                                                const float* __restrict__ g1,
                                                const float* __restrict__ b1) {
    int i = blockIdx.x * 256 + threadIdx.x;
    size_t base = (size_t)i * 4;
    int c = (int)((base >> 14) & 127);
    int b = (int)(base >> 21);
    int br = c >> 6;
    int co = c & 63;
    int sid = (br * 8 + b) * 16 + (co >> 2);
    float m = gn_stat[sid * 2];
    float rs = gn_stat[sid * 2 + 1];
    const float* gg = br ? g1 : g0;
    const float* bb = br ? b1 : b0;
    float ga = gg[co] * rs, be = bb[co] - m * gg[co] * rs;
    f32x4 v;
    if (F16IN) {
        short4v p = *(const short4v*)&cvout[base];
        v.x = h2f((unsigned short)p[0]); v.y = h2f((unsigned short)p[1]);
        v.z = h2f((unsigned short)p[2]); v.w = h2f((unsigned short)p[3]);
    } else {
        v = *(f32x4*)&out[base];
    }
    f32x4 r;
    r.x = fmaxf(fmaf(v.x, ga, be), 0.f);
    r.y = fmaxf(fmaf(v.y, ga, be), 0.f);
    r.z = fmaxf(fmaf(v.z, ga, be), 0.f);
    r.w = fmaxf(fmaf(v.w, ga, be), 0.f);
    *(f32x4*)&out[base] = r;
}

extern "C" void kernel_launch(void* const* d_in, const int* in_sizes, int n_in,
                              void* d_out, int out_size, void* d_ws, size_t ws_size,
                              hipStream_t stream) {
    const float* x       = (const float*)d_in[0];
    const float* off_w0  = (const float*)d_in[1];
    const float* bn_g0   = (const float*)d_in[3];
    const float* bn_b0   = (const float*)d_in[4];
    const float* conv_w0 = (const float*)d_in[5];
    const float* conv_b0 = (const float*)d_in[6];
    const float* gn_g0   = (const float*)d_in[7];
    const float* gn_b0   = (const float*)d_in[8];
    const float* off_w1  = (const float*)d_in[9];
    const float* bn_g1   = (const float*)d_in[11];
    const float* bn_b1   = (const float*)d_in[12];
    const float* conv_w1 = (const float*)d_in[13];
    const float* conv_b1 = (const float*)d_in[14];
    const float* gn_g1   = (const float*)d_in[15];
    const float* gn_b1   = (const float*)d_in[16];

    char* ws = (char*)d_ws;
    unsigned short* xt2   = (unsigned short*)(ws + XT_OFF);
    unsigned short* wrh3  = (unsigned short*)(ws + WRH_OFF);
    unsigned short* woh2  = (unsigned short*)(ws + WOH_OFF);
    float* off_raw = (float*)(ws + RAW_OFF);
    float* bn_stat = (float*)(ws + BNS_OFF);
    float* gnp     = (float*)(ws + GNP_OFF);
    float* gn_stat = (float*)(ws + GNS_OFF);
    unsigned short* cvout = (unsigned short*)(ws + CVOUT_OFF);
    float* out = (float*)d_out;

    bool f16path = (ws_size >= WS_NEED_F16);

    cvt_x<<<512, 256, 0, stream>>>(x, xt2);
    repack_all<<<360, 256, 0, stream>>>(conv_w0, conv_w1, off_w0, off_w1, wrh3, woh2);
    off_mfma<<<1024, 256, 0, stream>>>(xt2, woh2, off_raw, gnp);
    bn_fin2<<<18, 256, 0, stream>>>(gnp, bn_stat);
    if (f16path) {
        snake9<true><<<2048, 256, 0, stream>>>(xt2, wrh3, conv_b0, conv_b1, off_raw, bn_stat,
                                               bn_g0, bn_b0, bn_g1, bn_b1, out, cvout, gnp);
        gn_reduce<<<256, 256, 0, stream>>>(gnp, gn_stat);
        gn_apply<true><<<16384, 256, 0, stream>>>(out, cvout, gn_stat, gn_g0, gn_b0, gn_g1, gn_b1);
    } else {
        snake9<false><<<2048, 256, 0, stream>>>(xt2, wrh3, conv_b0, conv_b1, off_raw, bn_stat,
                                                bn_g0, bn_b0, bn_g1, bn_b1, out, cvout, gnp);
        gn_reduce<<<256, 256, 0, stream>>>(gnp, gn_stat);
        gn_apply<false><<<16384, 256, 0, stream>>>(out, cvout, gn_stat, gn_g0, gn_b0, gn_g1, gn_b1);
    }
}